// Round 7
// baseline (97.456 us; speedup 1.0000x reference)
//
#include <hip/hip_runtime.h>
#include <hip/hip_bf16.h>

// QLSTM: T=512, B=256, D_IN=128, D_H=128.
// Gates are per-batch SCALARS broadcast over hidden dim => h,c uniform across
// hidden dim. comb@W[0] = x@W[0][:128] + h*sum(W[0][128:]).
// Pipeline: (1) xz GEMV -> packed float4 (pre-scaled by 1/2pi)  (mem-bound),
//           (2) 512-step scan: 4 blocks x 64 threads, ONE LANE = ONE BATCH,
//               depth-8 prefetch in NAMED float4s, each refill PINNED in its
//               step slot by sched_barrier(0) so the scheduler cannot sink it
//               to the use point (R6 failure: loads sunk -> 200cy exposed/step),
//           (3) broadcast h[t,b] to 128 cols + hx/cx tails (write-bound).

constexpr int T = 512;
constexpr int Bsz = 256;
constexpr int R = T * Bsz;          // 131072 rows
constexpr float INV2PI = 0.15915494309189535f;

// ---------------- Kernel 1: xz[row] = float4(zf,zi,zu,zo)/(2pi), row = t*B+b
__global__ __launch_bounds__(256) void xz_kernel(
    const float* __restrict__ x,
    const float* __restrict__ Wf, const float* __restrict__ bf, const float* __restrict__ tf,
    const float* __restrict__ Wi, const float* __restrict__ bi, const float* __restrict__ ti,
    const float* __restrict__ Wu, const float* __restrict__ bu, const float* __restrict__ tu,
    const float* __restrict__ Wo, const float* __restrict__ bo, const float* __restrict__ to_,
    float4* __restrict__ xz)
{
    const int wglobal = blockIdx.x * 4 + (threadIdx.x >> 6);   // 0..8191
    const int lane = threadIdx.x & 63;
    const int hl = lane & 31;            // lane within half-wave
    const int half = lane >> 5;          // which row of the pair

    const float4 wfv = ((const float4*)Wf)[hl];
    const float4 wiv = ((const float4*)Wi)[hl];
    const float4 wuv = ((const float4*)Wu)[hl];
    const float4 wov = ((const float4*)Wo)[hl];

    const float cf = bf[0] + tf[0];
    const float ci = bi[0] + ti[0];
    const float cu = bu[0] + tu[0];
    const float co = bo[0] + to_[0];

    for (int it = 0; it < 8; ++it) {
        const int row = (it * 8192 + wglobal) * 2 + half;
        const float4 xv = *(const float4*)(x + (size_t)row * 128 + hl * 4);

        float pf = xv.x * wfv.x + xv.y * wfv.y + xv.z * wfv.z + xv.w * wfv.w;
        float pi = xv.x * wiv.x + xv.y * wiv.y + xv.z * wiv.z + xv.w * wiv.w;
        float pu = xv.x * wuv.x + xv.y * wuv.y + xv.z * wuv.z + xv.w * wuv.w;
        float po = xv.x * wov.x + xv.y * wov.y + xv.z * wov.z + xv.w * wov.w;

#pragma unroll
        for (int off = 16; off; off >>= 1) {
            pf += __shfl_xor(pf, off, 64);
            pi += __shfl_xor(pi, off, 64);
            pu += __shfl_xor(pu, off, 64);
            po += __shfl_xor(po, off, 64);
        }
        if (hl == 0) {
            xz[row] = make_float4((pf + cf) * INV2PI, (pi + ci) * INV2PI,
                                  (pu + cu) * INV2PI, (po + co) * INV2PI);
        }
    }
}

// ---------------- Kernel 2: sequential scan, one lane per batch element.
// tanh(c), |c|<=~2.1: Pade[5/4] c(945+105c^2+c^4)/(945+420c^2+15c^4), err ~2e-5.
__device__ __forceinline__ float tanh_p54(float c) {
    const float c2 = c * c;
    const float c4 = c2 * c2;
    const float num = fmaf(c2, 105.0f, 945.0f) + c4;
    const float den = fmaf(c4, 15.0f, fmaf(c2, 420.0f, 945.0f));
    return c * num * __builtin_amdgcn_rcpf(den);
}
// sigmoid(cos-arg v), |v|<=1: 0.5 + 0.5*tanh(v/2), odd deg-7 folded (err ~1e-5).
__device__ __forceinline__ float sigp(float v) {
    const float v2 = v * v;
    float p = fmaf(v2, -0.000108281f, 0.00188244f);
    p = fmaf(v2, p, -0.0206916f);
    p = fmaf(v2, p, 0.249976f);
    return fmaf(v, p, 0.5f);
}
// tanh(v), |v|<=1: odd deg-7 (err ~3e-4).
__device__ __forceinline__ float tanp(float v) {
    const float v2 = v * v;
    float p = fmaf(v2, -0.0277200f, 0.120476f);
    p = fmaf(v2, p, -0.331066f);
    p = fmaf(v2, p, 0.999904f);
    return v * p;
}

__device__ __forceinline__ float wsum(const float* __restrict__ W, int lane) {
    float s = W[128 + lane] + W[192 + lane];
#pragma unroll
    for (int off = 32; off; off >>= 1) s += __shfl_xor(s, off, 64);
    return s;  // butterfly: all lanes hold the sum
}

__global__ __launch_bounds__(64, 1) void scan_kernel(
    const float4* __restrict__ xz,
    const float* __restrict__ Wf, const float* __restrict__ Wi,
    const float* __restrict__ Wu, const float* __restrict__ Wo,
    float* __restrict__ hscan, float* __restrict__ cfin)
{
    const int lane = threadIdx.x;
    const int batch = blockIdx.x * 64 + lane;

    const float swf = wsum(Wf, lane) * INV2PI;
    const float swi = wsum(Wi, lane) * INV2PI;
    const float swu = wsum(Wu, lane) * INV2PI;
    const float swo = wsum(Wo, lane) * INV2PI;

    const float4* xzp = xz + batch;        // stride Bsz float4s per t
    float* hp = hscan + batch;

    // depth-8 prefetch in NAMED registers
    float4 z0 = xzp[0 * Bsz], z1 = xzp[1 * Bsz], z2 = xzp[2 * Bsz], z3 = xzp[3 * Bsz];
    float4 z4 = xzp[4 * Bsz], z5 = xzp[5 * Bsz], z6 = xzp[6 * Bsz], z7 = xzp[7 * Bsz];

    // carried state: c, tc = tanh(c), os_g = o * sw_g   (h = o*tc only for store)
    float c = 0.0f, tc = 0.0f;
    float osf = 0.0f, osi = 0.0f, osu = 0.0f, oso = 0.0f;

#define QSTEP(Z)                                                  \
    {                                                             \
        const float uf = fmaf(tc, osf, (Z).x);                    \
        const float ui = fmaf(tc, osi, (Z).y);                    \
        const float uu = fmaf(tc, osu, (Z).z);                    \
        const float uo = fmaf(tc, oso, (Z).w);                    \
        const float vf = __builtin_amdgcn_cosf(uf);               \
        const float vi = __builtin_amdgcn_cosf(ui);               \
        const float vu = __builtin_amdgcn_cosf(uu);               \
        const float vo = __builtin_amdgcn_cosf(uo);               \
        const float f  = sigp(vf);                                \
        const float i  = sigp(vi);                                \
        const float o  = sigp(vo);                                \
        const float g  = tanp(vu);                                \
        c  = fmaf(f, c, i * g);                                   \
        tc = tanh_p54(c);                                         \
        osf = o * swf; osi = o * swi;                             \
        osu = o * swu; oso = o * swo;                             \
        *hp = o * tc;                                             \
        hp += Bsz;                                                \
    }
// Pin the refill in its step slot: the machine scheduler may not move any
// instruction across sched_barrier(0), so the load issued here stays ~7 steps
// (~700 cy) ahead of its consumer instead of being sunk to the use point.
#define QSTEP_REFILL(Z, PRE)                                      \
    QSTEP(Z);                                                     \
    (Z) = (PRE);                                                  \
    __builtin_amdgcn_sched_barrier(0);

    for (int tb = 0; tb < T - 8; tb += 8) {
        const float4* pr = xzp + (size_t)(tb + 8) * Bsz;
        QSTEP_REFILL(z0, pr[0 * Bsz]);
        QSTEP_REFILL(z1, pr[1 * Bsz]);
        QSTEP_REFILL(z2, pr[2 * Bsz]);
        QSTEP_REFILL(z3, pr[3 * Bsz]);
        QSTEP_REFILL(z4, pr[4 * Bsz]);
        QSTEP_REFILL(z5, pr[5 * Bsz]);
        QSTEP_REFILL(z6, pr[6 * Bsz]);
        QSTEP_REFILL(z7, pr[7 * Bsz]);
    }
    // epilogue: last 8 steps, no refill
    QSTEP(z0); QSTEP(z1); QSTEP(z2); QSTEP(z3);
    QSTEP(z4); QSTEP(z5); QSTEP(z6); QSTEP(z7);
#undef QSTEP_REFILL
#undef QSTEP

    cfin[batch] = c;
}

// ---------------- Kernel 3: broadcast h[t,b] across 128 hidden cols, + hx/cx tails.
__global__ __launch_bounds__(256) void bcast_kernel(
    const float* __restrict__ hscan, const float* __restrict__ cfin,
    float4* __restrict__ out)
{
    const unsigned i = blockIdx.x * 256u + threadIdx.x;  // float4 index
    const unsigned row = i >> 5;                          // output row (128 floats)
    float v;
    if (row < (unsigned)R) {
        v = hscan[row];
    } else {
        const unsigned r2 = row - (unsigned)R;
        v = (r2 < (unsigned)Bsz) ? hscan[(T - 1) * Bsz + r2] : cfin[r2 - (unsigned)Bsz];
    }
    out[i] = make_float4(v, v, v, v);
}

extern "C" void kernel_launch(void* const* d_in, const int* in_sizes, int n_in,
                              void* d_out, int out_size, void* d_ws, size_t ws_size,
                              hipStream_t stream)
{
    const float* x  = (const float*)d_in[0];
    const float* Wf = (const float*)d_in[1];
    const float* bf = (const float*)d_in[2];
    const float* tf = (const float*)d_in[3];
    const float* Wi = (const float*)d_in[4];
    const float* bi = (const float*)d_in[5];
    const float* ti = (const float*)d_in[6];
    const float* Wu = (const float*)d_in[7];
    const float* bu = (const float*)d_in[8];
    const float* tu = (const float*)d_in[9];
    const float* Wo = (const float*)d_in[10];
    const float* bo = (const float*)d_in[11];
    const float* to_ = (const float*)d_in[12];

    float* ws    = (float*)d_ws;
    float4* xz   = (float4*)ws;       // R float4s  (4*R floats)
    float* hscan = ws + 4 * R;        // R floats
    float* cfin  = ws + 5 * R;        // Bsz floats

    xz_kernel<<<2048, 256, 0, stream>>>(x, Wf, bf, tf, Wi, bi, ti, Wu, bu, tu, Wo, bo, to_, xz);
    scan_kernel<<<4, 64, 0, stream>>>(xz, Wf, Wi, Wu, Wo, hscan, cfin);

    const int total_f4 = (R + 2 * Bsz) * 32;              // 4,210,688
    bcast_kernel<<<total_f4 / 256, 256, 0, stream>>>(hscan, cfin, (float4*)d_out);
}